// Round 10
// baseline (398.216 us; speedup 1.0000x reference)
//
#include <hip/hip_runtime.h>
#include <hip/hip_bf16.h>

#define N_ATOMS 10000
#define N_PAIR  100000
#define F_DIM   128
#define N_HEAD  4
#define FH      32
#define N_DEG   3
#define M_TOT   15
#define K_RBF   32
#define R_OUT   (N_ATOMS * M_TOT)
#define PPB     50                   // pairs per chunk in k_aggc

typedef __attribute__((ext_vector_type(8))) short short8;   // 8 bf16 = 4 VGPRs
typedef __attribute__((ext_vector_type(4))) float f32x4;

union frag_cast { int i[4]; short8 s; };
union h4u { ushort4 u; _Float16 h[4]; };
union h1u { unsigned short u; _Float16 h; };

__device__ __forceinline__ float sspf(float v) {
    float sp = fmaxf(v, 0.f) + log1pf(expf(-fabsf(v)));
    return sp - 0.69314718055994531f;
}

__device__ __forceinline__ unsigned short bf16_rne(float x) {
    unsigned int u = __float_as_uint(x);
    unsigned int r = u + 0x7fffu + ((u >> 16) & 1u);
    return (unsigned short)(r >> 16);
}
__device__ __forceinline__ float bf16_tof(unsigned short h) {
    return __uint_as_float(((unsigned int)h) << 16);
}

// ---------------- out pre-fill with b_out broadcast -------------------------
__global__ __launch_bounds__(256) void k_binit(
    const float* __restrict__ b, float4* __restrict__ out, int n4)
{
    int i = blockIdx.x * 256 + threadIdx.x;
    int stride = gridDim.x * 256;
    for (; i < n4; i += stride) {
        int c4 = i & 31;                       // 32 float4 per 128-col row
        out[i] = *(const float4*)(b + c4 * 4); // L1-hot broadcast
    }
}

// ---------------- Generic 128-col GEMM (fp32, used for x@W_in only) ---------
__global__ __launch_bounds__(256) void k_gemm128(
    const float* __restrict__ A, const float* __restrict__ B,
    const float* __restrict__ bias, float* __restrict__ C, int rows)
{
    __shared__ float As[32][132];
    __shared__ float Bs[32][132];
    int r0 = blockIdx.x * 128;
    int t = threadIdx.x;
    int ty = t >> 4, tx = t & 15;

    float acc[8][8];
    #pragma unroll
    for (int i = 0; i < 8; ++i)
        #pragma unroll
        for (int j = 0; j < 8; ++j) acc[i][j] = 0.f;

    for (int k0 = 0; k0 < 128; k0 += 32) {
        #pragma unroll
        for (int r = 0; r < 16; ++r) {
            int idx = t + 256 * r;
            int row = idx >> 5, kk = idx & 31;
            int grow = r0 + row;
            As[kk][row] = (grow < rows) ? A[grow * 128 + k0 + kk] : 0.f;
        }
        #pragma unroll
        for (int r = 0; r < 16; ++r) {
            int idx = t + 256 * r;
            int kk = idx >> 7, c = idx & 127;
            Bs[kk][c] = B[(k0 + kk) * 128 + c];
        }
        __syncthreads();

        #pragma unroll
        for (int kk = 0; kk < 32; ++kk) {
            float a[8], b[8];
            *(float4*)&a[0] = *(const float4*)&As[kk][ty * 4];
            *(float4*)&a[4] = *(const float4*)&As[kk][64 + ty * 4];
            *(float4*)&b[0] = *(const float4*)&Bs[kk][tx * 4];
            *(float4*)&b[4] = *(const float4*)&Bs[kk][64 + tx * 4];
            #pragma unroll
            for (int i = 0; i < 8; ++i)
                #pragma unroll
                for (int j = 0; j < 8; ++j)
                    acc[i][j] = fmaf(a[i], b[j], acc[i][j]);
        }
        __syncthreads();
    }

    float bj[8];
    #pragma unroll
    for (int j = 0; j < 4; ++j) { bj[j] = bias[tx * 4 + j]; bj[4 + j] = bias[64 + tx * 4 + j]; }

    #pragma unroll
    for (int i = 0; i < 8; ++i) {
        int row = r0 + ((i < 4) ? (ty * 4 + i) : (64 + ty * 4 + (i - 4)));
        if (row < rows) {
            float4 v0, v1;
            v0.x = acc[i][0] + bj[0]; v0.y = acc[i][1] + bj[1];
            v0.z = acc[i][2] + bj[2]; v0.w = acc[i][3] + bj[3];
            v1.x = acc[i][4] + bj[4]; v1.y = acc[i][5] + bj[5];
            v1.z = acc[i][6] + bj[6]; v1.w = acc[i][7] + bj[7];
            *(float4*)&C[row * 128 + tx * 4] = v0;
            *(float4*)&C[row * 128 + 64 + tx * 4] = v1;
        }
    }
}

// ---------------- Q/K projection: 32 atoms/block (313 blocks) ---------------
__global__ __launch_bounds__(384) void k_qk(
    const float* __restrict__ xh, const float* __restrict__ W_Q,
    const float* __restrict__ W_K, float* __restrict__ Q, float* __restrict__ K)
{
    __shared__ float xfs[32][128];
    int t = threadIdx.x;                 // == e
    int h = (t >> 5) & 3;
    float wq[32], wk[32];
    const float4* wqp = (const float4*)(W_Q + t * 32);
    const float4* wkp = (const float4*)(W_K + t * 32);
    #pragma unroll
    for (int j4 = 0; j4 < 8; ++j4) {
        float4 a = wqp[j4], b = wkp[j4];
        wq[4 * j4 + 0] = a.x; wq[4 * j4 + 1] = a.y; wq[4 * j4 + 2] = a.z; wq[4 * j4 + 3] = a.w;
        wk[4 * j4 + 0] = b.x; wk[4 * j4 + 1] = b.y; wk[4 * j4 + 2] = b.z; wk[4 * j4 + 3] = b.w;
    }
    int ab = blockIdx.x * 32;
    for (int idx = t; idx < 4096; idx += 384) {
        int aa = idx >> 7, f = idx & 127;
        int ag = ab + aa;
        xfs[aa][f] = (ag < N_ATOMS) ? xh[ag * 128 + f] : 0.f;
    }
    __syncthreads();
    for (int aa = 0; aa < 32; ++aa) {
        int ag = ab + aa;
        if (ag >= N_ATOMS) break;
        const float4* xv = (const float4*)&xfs[aa][h * 32];
        float q0 = 0.f, q1 = 0.f, k0 = 0.f, k1 = 0.f;
        #pragma unroll
        for (int j4 = 0; j4 < 8; j4 += 2) {
            float4 x0 = xv[j4], x1 = xv[j4 + 1];
            q0 = fmaf(wq[4 * j4 + 0], x0.x, q0); q0 = fmaf(wq[4 * j4 + 1], x0.y, q0);
            q0 = fmaf(wq[4 * j4 + 2], x0.z, q0); q0 = fmaf(wq[4 * j4 + 3], x0.w, q0);
            q1 = fmaf(wq[4 * j4 + 4], x1.x, q1); q1 = fmaf(wq[4 * j4 + 5], x1.y, q1);
            q1 = fmaf(wq[4 * j4 + 6], x1.z, q1); q1 = fmaf(wq[4 * j4 + 7], x1.w, q1);
            k0 = fmaf(wk[4 * j4 + 0], x0.x, k0); k0 = fmaf(wk[4 * j4 + 1], x0.y, k0);
            k0 = fmaf(wk[4 * j4 + 2], x0.z, k0); k0 = fmaf(wk[4 * j4 + 3], x0.w, k0);
            k1 = fmaf(wk[4 * j4 + 4], x1.x, k1); k1 = fmaf(wk[4 * j4 + 5], x1.y, k1);
            k1 = fmaf(wk[4 * j4 + 6], x1.z, k1); k1 = fmaf(wk[4 * j4 + 7], x1.w, k1);
        }
        Q[ag * 384 + t] = q0 + q1;
        K[ag * 384 + t] = k0 + k1;
    }
}

// ---------------- W_f2 -> transposed hi/lo bf16  [e][k] ---------------------
__global__ __launch_bounds__(256) void k_cvt_w2(
    const float* __restrict__ W, unsigned short* __restrict__ Wh,
    unsigned short* __restrict__ Wl)
{
    int idx = blockIdx.x * 256 + threadIdx.x;   // 12288 total
    if (idx < 12288) {
        int e = idx >> 5, k = idx & 31;
        float v = W[k * 384 + e];               // W_f2 is [32][384]
        unsigned short h = bf16_rne(v);
        unsigned short l = bf16_rne(v - bf16_tof(h));
        Wh[e * 32 + k] = h;
        Wl[e * 32 + k] = l;
    }
}

// ---------------- Pair kernel: MFMA for h1 @ W_f2 ---------------------------
__global__ __launch_bounds__(256) void k_pair(
    const float* __restrict__ rbf, const float* __restrict__ phi,
    const float* __restrict__ mask, const int* __restrict__ idx_i,
    const int* __restrict__ idx_j, const float* __restrict__ W_f1,
    const float* __restrict__ b_f1, const unsigned short* __restrict__ W2h,
    const unsigned short* __restrict__ W2l, const float* __restrict__ b_f2,
    const float* __restrict__ Q, const float* __restrict__ K,
    float* __restrict__ alpha)
{
    __shared__ float g_s[16][388];            // 24.8 KB; also staging for rbf/W_f1
    __shared__ unsigned int h1p_s[16][36];    // packed (hi<<16)|lo bf16, padded
    __shared__ int   i_s[16];
    __shared__ int   j_s[16];
    __shared__ float phim_s[16];              // phi * m^2 * 1/sqrt(32)

    float (*rbf_s)[33] = (float (*)[33])(&g_s[0][0]);           // 16 rows
    float (*wf1_s)[33] = (float (*)[33])(&g_s[0][0] + 16 * 33); // 32 rows

    int t = threadIdx.x;
    int p0 = blockIdx.x * 16;                 // N_PAIR = 6250*16 exactly

    for (int idx = t; idx < 1536; idx += 256) {
        if (idx < 512) {
            rbf_s[idx >> 5][idx & 31] = rbf[p0 * 32 + idx];
        } else {
            int k = idx - 512;
            wf1_s[k >> 5][k & 31] = W_f1[k];
        }
    }
    if (t < 16) {
        int pg = p0 + t;
        i_s[t] = idx_i[pg];
        j_s[t] = idx_j[pg];
        float m = mask[pg];
        phim_s[t] = phi[pg] * m * m * 0.17677669529663687f;
    }
    __syncthreads();

    {
        int p = t >> 4, c0 = (t & 15) * 2;
        float acc0 = b_f1[c0], acc1 = b_f1[c0 + 1];
        #pragma unroll
        for (int k = 0; k < 32; ++k) {
            float rv = rbf_s[p][k];
            acc0 = fmaf(rv, wf1_s[k][c0], acc0);
            acc1 = fmaf(rv, wf1_s[k][c0 + 1], acc1);
        }
        float h0 = sspf(acc0), h1v = sspf(acc1);
        unsigned short hh0 = bf16_rne(h0);
        unsigned short ll0 = bf16_rne(h0 - bf16_tof(hh0));
        unsigned short hh1 = bf16_rne(h1v);
        unsigned short ll1 = bf16_rne(h1v - bf16_tof(hh1));
        h1p_s[p][c0]     = ((unsigned int)hh0 << 16) | (unsigned int)ll0;
        h1p_s[p][c0 + 1] = ((unsigned int)hh1 << 16) | (unsigned int)ll1;
    }
    __syncthreads();

    #pragma unroll
    for (int it = 0; it < 6; ++it) {
        int idx = it * 256 + t;               // 0..1535 = 16 pairs x 96 float4
        int p = idx / 96;
        int c4 = idx - p * 96;
        const float4* qp = (const float4*)(Q + i_s[p] * 384) + c4;
        const float4* kp = (const float4*)(K + j_s[p] * 384) + c4;
        float4 qv = *qp, kv = *kp;
        float4 gv;
        gv.x = qv.x * kv.x; gv.y = qv.y * kv.y;
        gv.z = qv.z * kv.z; gv.w = qv.w * kv.w;
        *(float4*)&g_s[p][c4 * 4] = gv;
    }
    __syncthreads();

    int wave = t >> 6, lane = t & 63;
    int quad = lane >> 4, l15 = lane & 15;

    short8 ah, al;
    {
        const unsigned int* hp = &h1p_s[l15][quad * 8];
        uint4 u01 = *(const uint4*)hp;
        uint4 u23 = *(const uint4*)(hp + 4);
        unsigned int u[8] = {u01.x, u01.y, u01.z, u01.w, u23.x, u23.y, u23.z, u23.w};
        frag_cast fh, fl;
        #pragma unroll
        for (int q = 0; q < 4; ++q) {
            unsigned int a0 = u[2 * q], a1 = u[2 * q + 1];
            fh.i[q] = (int)((a0 >> 16) | (a1 & 0xffff0000u));
            fl.i[q] = (int)((a0 & 0xffffu) | (a1 << 16));
        }
        ah = fh.s;
        al = fl.s;
    }

    #pragma unroll
    for (int dd = 0; dd < 3; ++dd) {
        int dh = wave * 3 + dd;
        int e_base = dh * 32;
        short8 bh0 = *(const short8*)(W2h + (e_base + l15) * 32 + quad * 8);
        short8 bl0 = *(const short8*)(W2l + (e_base + l15) * 32 + quad * 8);
        short8 bh1 = *(const short8*)(W2h + (e_base + 16 + l15) * 32 + quad * 8);
        short8 bl1 = *(const short8*)(W2l + (e_base + 16 + l15) * 32 + quad * 8);
        float b2v0 = b_f2[e_base + l15];
        float b2v1 = b_f2[e_base + 16 + l15];

        f32x4 s0 = {0.f, 0.f, 0.f, 0.f};
        f32x4 s1 = {0.f, 0.f, 0.f, 0.f};
        s0 = __builtin_amdgcn_mfma_f32_16x16x32_bf16(ah, bh0, s0, 0, 0, 0);
        s1 = __builtin_amdgcn_mfma_f32_16x16x32_bf16(ah, bh1, s1, 0, 0, 0);
        s0 = __builtin_amdgcn_mfma_f32_16x16x32_bf16(al, bh0, s0, 0, 0, 0);
        s1 = __builtin_amdgcn_mfma_f32_16x16x32_bf16(al, bh1, s1, 0, 0, 0);
        s0 = __builtin_amdgcn_mfma_f32_16x16x32_bf16(ah, bl0, s0, 0, 0, 0);
        s1 = __builtin_amdgcn_mfma_f32_16x16x32_bf16(ah, bl1, s1, 0, 0, 0);

        float vsum[4];
        #pragma unroll
        for (int r = 0; r < 4; ++r) {
            int prow = quad * 4 + r;
            float v = (s0[r] + b2v0) * g_s[prow][e_base + l15]
                    + (s1[r] + b2v1) * g_s[prow][e_base + 16 + l15];
            #pragma unroll
            for (int off = 8; off >= 1; off >>= 1)
                v += __shfl_xor(v, off, 16);
            vsum[r] = v;
        }
        if (l15 == 0) {
            #pragma unroll
            for (int r = 0; r < 4; ++r) {
                int prow = quad * 4 + r;
                alpha[(p0 + prow) * 12 + dh] = vsum[r] * phim_s[prow];
            }
        }
    }
}

// ---------------- per-head x_head @ W_out -> fp16 packed [atom][c][h] -------
__global__ __launch_bounds__(512) void k_xw(
    const float* __restrict__ xh, const float* __restrict__ W,
    unsigned short* __restrict__ xwh)
{
    __shared__ float xs[32][132];
    int t = threadIdx.x;
    int a0 = blockIdx.x * 32;
    for (int idx = t; idx < 1024; idx += 512) {
        int row = idx >> 5, c4 = (idx & 31) * 4;
        int ga = a0 + row;
        float4 v = make_float4(0.f, 0.f, 0.f, 0.f);
        if (ga < N_ATOMS) v = *(const float4*)(xh + ga * 128 + c4);
        *(float4*)&xs[row][c4] = v;
    }
    __syncthreads();

    int c = t >> 2, h = t & 3;
    float w[32];
    #pragma unroll
    for (int k = 0; k < 32; ++k) w[k] = W[(h * 32 + k) * 128 + c];

    for (int a = 0; a < 32; ++a) {
        int ga = a0 + a;
        if (ga >= N_ATOMS) break;      // uniform across block
        float acc = 0.f;
        #pragma unroll
        for (int k = 0; k < 32; ++k)
            acc = fmaf(xs[a][h * 32 + k], w[k], acc);
        h1u pk;
        pk.h = (_Float16)acc;
        xwh[(long)ga * 512 + t] = pk.u;
    }
}

// ---------------- Chunked pair-streaming aggregation -> FINAL out -----------
// 2000 chunks (PPB=50, atomic-edge count unchanged) x 4 waves per chunk:
// (cols 0-63 / 64-127) x (m 0-7 / m 8-14). m-split aligns with degree
// boundaries: m<8 needs alpha[0..7] (sd0,sd1), m>=8 needs alpha[8..11] (sd2)
// -> no redundant work, flushes disjoint. 8000 waves total. Depth-4 prefetch
// on the random xwh gather covers L3-class latency.
template<int M0, int MC>
__device__ __forceinline__ void flush_mrange(float* __restrict__ out, int a,
                                             const float* acc, float bout,
                                             int t, bool interior)
{
    float* base = out + (long)a * (M_TOT * 128) + M0 * 128 + t;
    if (interior) {
        #pragma unroll
        for (int m = 0; m < MC; ++m) base[m * 128] = acc[m] + bout;
    } else {
        #pragma unroll
        for (int m = 0; m < MC; ++m) atomicAdd(&base[m * 128], acc[m]);
    }
}

__global__ __launch_bounds__(512) void k_aggc(
    const unsigned short* __restrict__ xwh, const float* __restrict__ alpha,
    const float* __restrict__ sph, const int* __restrict__ idx_i,
    const int* __restrict__ idx_j, const float* __restrict__ mask,
    const float* __restrict__ b_out, float* __restrict__ out)
{
    const ushort4* xwp = (const ushort4*)xwh;
    int tid   = threadIdx.x;
    int wave  = tid >> 6;                       // 0..7
    int lane  = tid & 63;
    int chunk = blockIdx.x * 2 + (wave >> 2);   // 2 chunks per block
    int sub   = wave & 3;
    int mh    = sub >> 1;                       // 0: m 0..7, 1: m 8..14
    int t     = (sub & 1) * 64 + lane;          // output column c
    int g0    = chunk * PPB;
    int g1    = g0 + PPB;

    float bout = b_out[t];
    int prevA = (g0 > 0) ? idx_i[g0 - 1] : -1;
    int nextA = (g1 < N_PAIR) ? idx_i[g1] : -1;

    float acc[8];
    #pragma unroll
    for (int m = 0; m < 8; ++m) acc[m] = 0.f;

    int cur = idx_i[g0];
    bool started_inside = (cur != prevA);

    // depth-4 gather pipeline: rows p..p+3 in flight, j for p+4 ready
    int ja = idx_j[g0], jb = idx_j[g0 + 1], jc = idx_j[g0 + 2], jd = idx_j[g0 + 3];
    h4u x0, x1, x2, x3;
    x0.u = xwp[(long)ja * 128 + t];
    x1.u = xwp[(long)jb * 128 + t];
    x2.u = xwp[(long)jc * 128 + t];
    x3.u = xwp[(long)jd * 128 + t];
    int jn = idx_j[g0 + 4];                     // PPB >= 5

    for (int p = g0; p < g1; ++p) {
        h4u x4; x4.u = x3.u;
        int jn2 = 0;
        if (p + 4 < g1) {
            x4.u = xwp[(long)jn * 128 + t];     // issued before any use below
            if (p + 5 < g1) jn2 = idx_j[p + 5];
        }
        int ii = idx_i[p];
        if (ii != cur) {
            if (mh == 0) flush_mrange<0, 8>(out, cur, acc, bout, t, started_inside);
            else         flush_mrange<8, 7>(out, cur, acc, bout, t, started_inside);
            #pragma unroll
            for (int m = 0; m < 8; ++m) acc[m] = 0.f;
            cur = ii;
            started_inside = true;
        }
        float xw0 = (float)x0.h[0];
        float xw1 = (float)x0.h[1];
        float xw2 = (float)x0.h[2];
        float xw3 = (float)x0.h[3];
        float mv = mask[p];
        const float* ap = alpha + p * 12;
        const float* sp = sph + p * 15;
        if (mh == 0) {
            float sd0 = (ap[0] * xw0 + ap[1] * xw1 + ap[2] * xw2 + ap[3] * xw3) * mv;
            float sd1 = (ap[4] * xw0 + ap[5] * xw1 + ap[6] * xw2 + ap[7] * xw3) * mv;
            #pragma unroll
            for (int m = 0; m < 8; ++m) {
                float sdv = (m < 3) ? sd0 : sd1;
                acc[m] = fmaf(sp[m], sdv, acc[m]);
            }
        } else {
            float sd2 = (ap[8] * xw0 + ap[9] * xw1 + ap[10] * xw2 + ap[11] * xw3) * mv;
            #pragma unroll
            for (int m = 0; m < 7; ++m)
                acc[m] = fmaf(sp[8 + m], sd2, acc[m]);
        }
        x0.u = x1.u;
        x1.u = x2.u;
        x2.u = x3.u;
        x3.u = x4.u;
        jn = jn2;
    }
    bool interior = started_inside && (cur != nextA);
    if (mh == 0) flush_mrange<0, 8>(out, cur, acc, bout, t, interior);
    else         flush_mrange<8, 7>(out, cur, acc, bout, t, interior);
}

extern "C" void kernel_launch(void* const* d_in, const int* in_sizes, int n_in,
                              void* d_out, int out_size, void* d_ws, size_t ws_size,
                              hipStream_t stream) {
    const float* x        = (const float*)d_in[0];
    const float* rbf_ij   = (const float*)d_in[1];
    const float* sph_ij   = (const float*)d_in[2];
    const float* phi_r    = (const float*)d_in[3];
    const int*   idx_i    = (const int*)d_in[4];
    const int*   idx_j    = (const int*)d_in[5];
    const float* pmask    = (const float*)d_in[6];
    const float* W_Q      = (const float*)d_in[7];
    const float* W_K      = (const float*)d_in[8];
    const float* W_in     = (const float*)d_in[9];
    const float* b_in     = (const float*)d_in[10];
    const float* W_f1     = (const float*)d_in[11];
    const float* b_f1     = (const float*)d_in[12];
    const float* W_f2     = (const float*)d_in[13];
    const float* b_f2     = (const float*)d_in[14];
    const float* W_out    = (const float*)d_in[15];
    const float* b_out    = (const float*)d_in[16];
    float* out = (float*)d_out;

    float* ws    = (float*)d_ws;
    float* xh    = ws;                                   // 10000*128
    float* Qbuf  = xh + N_ATOMS * F_DIM;                 // 10000*384
    float* Kbuf  = Qbuf + N_ATOMS * 384;                 // 10000*384
    float* alpha = Kbuf + N_ATOMS * 384;                 // 100000*12
    unsigned short* W2h = (unsigned short*)(alpha + N_PAIR * 12); // 12288 bf16
    unsigned short* W2l = W2h + 12288;                    // 12288 bf16
    unsigned short* xwh = (unsigned short*)Qbuf; // reuse Q/K space after k_pair
                                                 // 10000*512 fp16 = 10.24 MB

    k_binit<<<2048, 256, 0, stream>>>(b_out, (float4*)d_out, R_OUT * 128 / 4);
    k_cvt_w2<<<48, 256, 0, stream>>>(W_f2, W2h, W2l);
    k_gemm128<<<(N_ATOMS + 127) / 128, 256, 0, stream>>>(x, W_in, b_in, xh, N_ATOMS);
    k_qk<<<(N_ATOMS + 31) / 32, 384, 0, stream>>>(xh, W_Q, W_K, Qbuf, Kbuf);
    k_pair<<<N_PAIR / 16, 256, 0, stream>>>(rbf_ij, phi_r, pmask, idx_i, idx_j,
                                            W_f1, b_f1, W2h, W2l, b_f2,
                                            Qbuf, Kbuf, alpha);
    k_xw<<<(N_ATOMS + 31) / 32, 512, 0, stream>>>(xh, W_out, xwh);
    k_aggc<<<N_PAIR / (2 * PPB), 512, 0, stream>>>(xwh, alpha, sph_ij, idx_i, idx_j,
                                                   pmask, b_out, out);
}

// Round 11
// 364.056 us; speedup vs baseline: 1.0938x; 1.0938x over previous
//
#include <hip/hip_runtime.h>
#include <hip/hip_bf16.h>

#define N_ATOMS 10000
#define N_PAIR  100000
#define F_DIM   128
#define N_HEAD  4
#define FH      32
#define N_DEG   3
#define M_TOT   15
#define K_RBF   32
#define R_OUT   (N_ATOMS * M_TOT)
#define PPB     50                   // pairs per chunk in k_aggc

typedef __attribute__((ext_vector_type(8))) short short8;   // 8 bf16 = 4 VGPRs
typedef __attribute__((ext_vector_type(4))) float f32x4;

union frag_cast { int i[4]; short8 s; };
union h4u { ushort4 u; _Float16 h[4]; };
union h1u { unsigned short u; _Float16 h; };

__device__ __forceinline__ float sspf(float v) {
    float sp = fmaxf(v, 0.f) + log1pf(expf(-fabsf(v)));
    return sp - 0.69314718055994531f;
}

__device__ __forceinline__ unsigned short bf16_rne(float x) {
    unsigned int u = __float_as_uint(x);
    unsigned int r = u + 0x7fffu + ((u >> 16) & 1u);
    return (unsigned short)(r >> 16);
}
__device__ __forceinline__ float bf16_tof(unsigned short h) {
    return __uint_as_float(((unsigned int)h) << 16);
}

// ---------------- out pre-fill with b_out broadcast -------------------------
__global__ __launch_bounds__(256) void k_binit(
    const float* __restrict__ b, float4* __restrict__ out, int n4)
{
    int i = blockIdx.x * 256 + threadIdx.x;
    int stride = gridDim.x * 256;
    for (; i < n4; i += stride) {
        int c4 = i & 31;                       // 32 float4 per 128-col row
        out[i] = *(const float4*)(b + c4 * 4); // L1-hot broadcast
    }
}

// ---------------- pack sph*mask into rec[p][12..27] -------------------------
// rec[p][32]: [0..11] alpha (written by k_pair), [12..26] sph*mask, [27] 0.
__global__ __launch_bounds__(256) void k_pack(
    const float* __restrict__ sph, const float* __restrict__ mask,
    float* __restrict__ rec)
{
    int idx = blockIdx.x * 256 + threadIdx.x;   // 100000*16
    int p = idx >> 4, m = idx & 15;
    if (p < N_PAIR) {
        float v = (m < 15) ? sph[p * 15 + m] * mask[p] : 0.f;
        rec[(long)p * 32 + 12 + m] = v;
    }
}

// ---------------- Generic 128-col GEMM (fp32, used for x@W_in only) ---------
__global__ __launch_bounds__(256) void k_gemm128(
    const float* __restrict__ A, const float* __restrict__ B,
    const float* __restrict__ bias, float* __restrict__ C, int rows)
{
    __shared__ float As[32][132];
    __shared__ float Bs[32][132];
    int r0 = blockIdx.x * 128;
    int t = threadIdx.x;
    int ty = t >> 4, tx = t & 15;

    float acc[8][8];
    #pragma unroll
    for (int i = 0; i < 8; ++i)
        #pragma unroll
        for (int j = 0; j < 8; ++j) acc[i][j] = 0.f;

    for (int k0 = 0; k0 < 128; k0 += 32) {
        #pragma unroll
        for (int r = 0; r < 16; ++r) {
            int idx = t + 256 * r;
            int row = idx >> 5, kk = idx & 31;
            int grow = r0 + row;
            As[kk][row] = (grow < rows) ? A[grow * 128 + k0 + kk] : 0.f;
        }
        #pragma unroll
        for (int r = 0; r < 16; ++r) {
            int idx = t + 256 * r;
            int kk = idx >> 7, c = idx & 127;
            Bs[kk][c] = B[(k0 + kk) * 128 + c];
        }
        __syncthreads();

        #pragma unroll
        for (int kk = 0; kk < 32; ++kk) {
            float a[8], b[8];
            *(float4*)&a[0] = *(const float4*)&As[kk][ty * 4];
            *(float4*)&a[4] = *(const float4*)&As[kk][64 + ty * 4];
            *(float4*)&b[0] = *(const float4*)&Bs[kk][tx * 4];
            *(float4*)&b[4] = *(const float4*)&Bs[kk][64 + tx * 4];
            #pragma unroll
            for (int i = 0; i < 8; ++i)
                #pragma unroll
                for (int j = 0; j < 8; ++j)
                    acc[i][j] = fmaf(a[i], b[j], acc[i][j]);
        }
        __syncthreads();
    }

    float bj[8];
    #pragma unroll
    for (int j = 0; j < 4; ++j) { bj[j] = bias[tx * 4 + j]; bj[4 + j] = bias[64 + tx * 4 + j]; }

    #pragma unroll
    for (int i = 0; i < 8; ++i) {
        int row = r0 + ((i < 4) ? (ty * 4 + i) : (64 + ty * 4 + (i - 4)));
        if (row < rows) {
            float4 v0, v1;
            v0.x = acc[i][0] + bj[0]; v0.y = acc[i][1] + bj[1];
            v0.z = acc[i][2] + bj[2]; v0.w = acc[i][3] + bj[3];
            v1.x = acc[i][4] + bj[4]; v1.y = acc[i][5] + bj[5];
            v1.z = acc[i][6] + bj[6]; v1.w = acc[i][7] + bj[7];
            *(float4*)&C[row * 128 + tx * 4] = v0;
            *(float4*)&C[row * 128 + 64 + tx * 4] = v1;
        }
    }
}

// ---------------- Q/K projection: 32 atoms/block (313 blocks) ---------------
__global__ __launch_bounds__(384) void k_qk(
    const float* __restrict__ xh, const float* __restrict__ W_Q,
    const float* __restrict__ W_K, float* __restrict__ Q, float* __restrict__ K)
{
    __shared__ float xfs[32][128];
    int t = threadIdx.x;                 // == e
    int h = (t >> 5) & 3;
    float wq[32], wk[32];
    const float4* wqp = (const float4*)(W_Q + t * 32);
    const float4* wkp = (const float4*)(W_K + t * 32);
    #pragma unroll
    for (int j4 = 0; j4 < 8; ++j4) {
        float4 a = wqp[j4], b = wkp[j4];
        wq[4 * j4 + 0] = a.x; wq[4 * j4 + 1] = a.y; wq[4 * j4 + 2] = a.z; wq[4 * j4 + 3] = a.w;
        wk[4 * j4 + 0] = b.x; wk[4 * j4 + 1] = b.y; wk[4 * j4 + 2] = b.z; wk[4 * j4 + 3] = b.w;
    }
    int ab = blockIdx.x * 32;
    for (int idx = t; idx < 4096; idx += 384) {
        int aa = idx >> 7, f = idx & 127;
        int ag = ab + aa;
        xfs[aa][f] = (ag < N_ATOMS) ? xh[ag * 128 + f] : 0.f;
    }
    __syncthreads();
    for (int aa = 0; aa < 32; ++aa) {
        int ag = ab + aa;
        if (ag >= N_ATOMS) break;
        const float4* xv = (const float4*)&xfs[aa][h * 32];
        float q0 = 0.f, q1 = 0.f, k0 = 0.f, k1 = 0.f;
        #pragma unroll
        for (int j4 = 0; j4 < 8; j4 += 2) {
            float4 x0 = xv[j4], x1 = xv[j4 + 1];
            q0 = fmaf(wq[4 * j4 + 0], x0.x, q0); q0 = fmaf(wq[4 * j4 + 1], x0.y, q0);
            q0 = fmaf(wq[4 * j4 + 2], x0.z, q0); q0 = fmaf(wq[4 * j4 + 3], x0.w, q0);
            q1 = fmaf(wq[4 * j4 + 4], x1.x, q1); q1 = fmaf(wq[4 * j4 + 5], x1.y, q1);
            q1 = fmaf(wq[4 * j4 + 6], x1.z, q1); q1 = fmaf(wq[4 * j4 + 7], x1.w, q1);
            k0 = fmaf(wk[4 * j4 + 0], x0.x, k0); k0 = fmaf(wk[4 * j4 + 1], x0.y, k0);
            k0 = fmaf(wk[4 * j4 + 2], x0.z, k0); k0 = fmaf(wk[4 * j4 + 3], x0.w, k0);
            k1 = fmaf(wk[4 * j4 + 4], x1.x, k1); k1 = fmaf(wk[4 * j4 + 5], x1.y, k1);
            k1 = fmaf(wk[4 * j4 + 6], x1.z, k1); k1 = fmaf(wk[4 * j4 + 7], x1.w, k1);
        }
        Q[ag * 384 + t] = q0 + q1;
        K[ag * 384 + t] = k0 + k1;
    }
}

// ---------------- W_f2 -> transposed hi/lo bf16  [e][k] ---------------------
__global__ __launch_bounds__(256) void k_cvt_w2(
    const float* __restrict__ W, unsigned short* __restrict__ Wh,
    unsigned short* __restrict__ Wl)
{
    int idx = blockIdx.x * 256 + threadIdx.x;   // 12288 total
    if (idx < 12288) {
        int e = idx >> 5, k = idx & 31;
        float v = W[k * 384 + e];               // W_f2 is [32][384]
        unsigned short h = bf16_rne(v);
        unsigned short l = bf16_rne(v - bf16_tof(h));
        Wh[e * 32 + k] = h;
        Wl[e * 32 + k] = l;
    }
}

// ---------------- Pair kernel: MFMA for h1 @ W_f2; alpha -> rec[p][0..11] ---
__global__ __launch_bounds__(256) void k_pair(
    const float* __restrict__ rbf, const float* __restrict__ phi,
    const float* __restrict__ mask, const int* __restrict__ idx_i,
    const int* __restrict__ idx_j, const float* __restrict__ W_f1,
    const float* __restrict__ b_f1, const unsigned short* __restrict__ W2h,
    const unsigned short* __restrict__ W2l, const float* __restrict__ b_f2,
    const float* __restrict__ Q, const float* __restrict__ K,
    float* __restrict__ rec)
{
    __shared__ float g_s[16][388];            // 24.8 KB; also staging for rbf/W_f1
    __shared__ unsigned int h1p_s[16][36];    // packed (hi<<16)|lo bf16, padded
    __shared__ int   i_s[16];
    __shared__ int   j_s[16];
    __shared__ float phim_s[16];              // phi * m^2 * 1/sqrt(32)

    float (*rbf_s)[33] = (float (*)[33])(&g_s[0][0]);           // 16 rows
    float (*wf1_s)[33] = (float (*)[33])(&g_s[0][0] + 16 * 33); // 32 rows

    int t = threadIdx.x;
    int p0 = blockIdx.x * 16;                 // N_PAIR = 6250*16 exactly

    for (int idx = t; idx < 1536; idx += 256) {
        if (idx < 512) {
            rbf_s[idx >> 5][idx & 31] = rbf[p0 * 32 + idx];
        } else {
            int k = idx - 512;
            wf1_s[k >> 5][k & 31] = W_f1[k];
        }
    }
    if (t < 16) {
        int pg = p0 + t;
        i_s[t] = idx_i[pg];
        j_s[t] = idx_j[pg];
        float m = mask[pg];
        phim_s[t] = phi[pg] * m * m * 0.17677669529663687f;
    }
    __syncthreads();

    {
        int p = t >> 4, c0 = (t & 15) * 2;
        float acc0 = b_f1[c0], acc1 = b_f1[c0 + 1];
        #pragma unroll
        for (int k = 0; k < 32; ++k) {
            float rv = rbf_s[p][k];
            acc0 = fmaf(rv, wf1_s[k][c0], acc0);
            acc1 = fmaf(rv, wf1_s[k][c0 + 1], acc1);
        }
        float h0 = sspf(acc0), h1v = sspf(acc1);
        unsigned short hh0 = bf16_rne(h0);
        unsigned short ll0 = bf16_rne(h0 - bf16_tof(hh0));
        unsigned short hh1 = bf16_rne(h1v);
        unsigned short ll1 = bf16_rne(h1v - bf16_tof(hh1));
        h1p_s[p][c0]     = ((unsigned int)hh0 << 16) | (unsigned int)ll0;
        h1p_s[p][c0 + 1] = ((unsigned int)hh1 << 16) | (unsigned int)ll1;
    }
    __syncthreads();

    #pragma unroll
    for (int it = 0; it < 6; ++it) {
        int idx = it * 256 + t;               // 0..1535 = 16 pairs x 96 float4
        int p = idx / 96;
        int c4 = idx - p * 96;
        const float4* qp = (const float4*)(Q + i_s[p] * 384) + c4;
        const float4* kp = (const float4*)(K + j_s[p] * 384) + c4;
        float4 qv = *qp, kv = *kp;
        float4 gv;
        gv.x = qv.x * kv.x; gv.y = qv.y * kv.y;
        gv.z = qv.z * kv.z; gv.w = qv.w * kv.w;
        *(float4*)&g_s[p][c4 * 4] = gv;
    }
    __syncthreads();

    int wave = t >> 6, lane = t & 63;
    int quad = lane >> 4, l15 = lane & 15;

    short8 ah, al;
    {
        const unsigned int* hp = &h1p_s[l15][quad * 8];
        uint4 u01 = *(const uint4*)hp;
        uint4 u23 = *(const uint4*)(hp + 4);
        unsigned int u[8] = {u01.x, u01.y, u01.z, u01.w, u23.x, u23.y, u23.z, u23.w};
        frag_cast fh, fl;
        #pragma unroll
        for (int q = 0; q < 4; ++q) {
            unsigned int a0 = u[2 * q], a1 = u[2 * q + 1];
            fh.i[q] = (int)((a0 >> 16) | (a1 & 0xffff0000u));
            fl.i[q] = (int)((a0 & 0xffffu) | (a1 << 16));
        }
        ah = fh.s;
        al = fl.s;
    }

    #pragma unroll
    for (int dd = 0; dd < 3; ++dd) {
        int dh = wave * 3 + dd;
        int e_base = dh * 32;
        short8 bh0 = *(const short8*)(W2h + (e_base + l15) * 32 + quad * 8);
        short8 bl0 = *(const short8*)(W2l + (e_base + l15) * 32 + quad * 8);
        short8 bh1 = *(const short8*)(W2h + (e_base + 16 + l15) * 32 + quad * 8);
        short8 bl1 = *(const short8*)(W2l + (e_base + 16 + l15) * 32 + quad * 8);
        float b2v0 = b_f2[e_base + l15];
        float b2v1 = b_f2[e_base + 16 + l15];

        f32x4 s0 = {0.f, 0.f, 0.f, 0.f};
        f32x4 s1 = {0.f, 0.f, 0.f, 0.f};
        s0 = __builtin_amdgcn_mfma_f32_16x16x32_bf16(ah, bh0, s0, 0, 0, 0);
        s1 = __builtin_amdgcn_mfma_f32_16x16x32_bf16(ah, bh1, s1, 0, 0, 0);
        s0 = __builtin_amdgcn_mfma_f32_16x16x32_bf16(al, bh0, s0, 0, 0, 0);
        s1 = __builtin_amdgcn_mfma_f32_16x16x32_bf16(al, bh1, s1, 0, 0, 0);
        s0 = __builtin_amdgcn_mfma_f32_16x16x32_bf16(ah, bl0, s0, 0, 0, 0);
        s1 = __builtin_amdgcn_mfma_f32_16x16x32_bf16(ah, bl1, s1, 0, 0, 0);

        float vsum[4];
        #pragma unroll
        for (int r = 0; r < 4; ++r) {
            int prow = quad * 4 + r;
            float v = (s0[r] + b2v0) * g_s[prow][e_base + l15]
                    + (s1[r] + b2v1) * g_s[prow][e_base + 16 + l15];
            #pragma unroll
            for (int off = 8; off >= 1; off >>= 1)
                v += __shfl_xor(v, off, 16);
            vsum[r] = v;
        }
        if (l15 == 0) {
            #pragma unroll
            for (int r = 0; r < 4; ++r) {
                int prow = quad * 4 + r;
                rec[(long)(p0 + prow) * 32 + dh] = vsum[r] * phim_s[prow];
            }
        }
    }
}

// ---------------- per-head x_head @ W_out -> fp16 packed [atom][c][h] -------
__global__ __launch_bounds__(512) void k_xw(
    const float* __restrict__ xh, const float* __restrict__ W,
    unsigned short* __restrict__ xwh)
{
    __shared__ float xs[32][132];
    int t = threadIdx.x;
    int a0 = blockIdx.x * 32;
    for (int idx = t; idx < 1024; idx += 512) {
        int row = idx >> 5, c4 = (idx & 31) * 4;
        int ga = a0 + row;
        float4 v = make_float4(0.f, 0.f, 0.f, 0.f);
        if (ga < N_ATOMS) v = *(const float4*)(xh + ga * 128 + c4);
        *(float4*)&xs[row][c4] = v;
    }
    __syncthreads();

    int c = t >> 2, h = t & 3;
    float w[32];
    #pragma unroll
    for (int k = 0; k < 32; ++k) w[k] = W[(h * 32 + k) * 128 + c];

    for (int a = 0; a < 32; ++a) {
        int ga = a0 + a;
        if (ga >= N_ATOMS) break;      // uniform across block
        float acc = 0.f;
        #pragma unroll
        for (int k = 0; k < 32; ++k)
            acc = fmaf(xs[a][h * 32 + k], w[k], acc);
        h1u pk;
        pk.h = (_Float16)acc;
        xwh[(long)ga * 512 + t] = pk.u;
    }
}

// ---------------- Chunked pair-streaming aggregation -> FINAL out -----------
// R8 structure: 2000 chunks (PPB=50) x 2 waves (cols 0-63 / 64-127), depth-2
// gather prefetch. Per-pair scalars come from one packed rec[p][32] record
// ([alpha(12), sph*mask(15), pad]) -> 7 float4 broadcasts instead of 28
// scalar loads. Interior segments direct-store acc+b_out; boundary segments
// atomicAdd onto the b_out-initialized out.
__device__ __forceinline__ void flush_acc(float* __restrict__ out, int a,
                                          const float* acc, float bout,
                                          int t, bool interior)
{
    float* base = out + (long)a * (M_TOT * 128) + t;
    if (interior) {
        #pragma unroll
        for (int m = 0; m < M_TOT; ++m) base[m * 128] = acc[m] + bout;
    } else {
        #pragma unroll
        for (int m = 0; m < M_TOT; ++m) atomicAdd(&base[m * 128], acc[m]);
    }
}

__global__ __launch_bounds__(512) void k_aggc(
    const unsigned short* __restrict__ xwh, const float* __restrict__ rec,
    const int* __restrict__ idx_i, const int* __restrict__ idx_j,
    const float* __restrict__ b_out, float* __restrict__ out)
{
    const ushort4* xwp = (const ushort4*)xwh;
    int tid  = threadIdx.x;
    int wave = tid >> 6;
    int lane = tid & 63;
    int chunk = blockIdx.x * 4 + (wave >> 1);   // 4 chunks per block
    int t    = (wave & 1) * 64 + lane;          // output column c (0..127)
    int g0   = chunk * PPB;
    int g1   = g0 + PPB;

    float bout = b_out[t];
    int prevA = (g0 > 0) ? idx_i[g0 - 1] : -1;
    int nextA = (g1 < N_PAIR) ? idx_i[g1] : -1;

    float acc[M_TOT];
    #pragma unroll
    for (int m = 0; m < M_TOT; ++m) acc[m] = 0.f;

    int cur = idx_i[g0];
    bool started_inside = (cur != prevA);

    // depth-2 gather pipeline: rows for p and p+1 in flight, j for p+2 ready
    int j0 = idx_j[g0];
    int j1 = idx_j[g0 + 1];
    h4u x0; x0.u = xwp[(long)j0 * 128 + t];
    h4u x1; x1.u = xwp[(long)j1 * 128 + t];
    int j2 = idx_j[g0 + 2];                     // PPB >= 3

    for (int p = g0; p < g1; ++p) {
        h4u x2; x2.u = x1.u;
        int j3 = 0;
        if (p + 2 < g1) {
            x2.u = xwp[(long)j2 * 128 + t];     // issued before any use below
            if (p + 3 < g1) j3 = idx_j[p + 3];
        }
        int ii = idx_i[p];
        if (ii != cur) {
            flush_acc(out, cur, acc, bout, t, started_inside);
            #pragma unroll
            for (int m = 0; m < M_TOT; ++m) acc[m] = 0.f;
            cur = ii;
            started_inside = true;
        }
        const float4* rp = (const float4*)(rec + (long)p * 32);
        float4 ra0 = rp[0], ra1 = rp[1], ra2 = rp[2];   // alpha[0..11]
        float4 rs0 = rp[3], rs1 = rp[4], rs2 = rp[5], rs3 = rp[6]; // sph*m
        float xw0 = (float)x0.h[0];
        float xw1 = (float)x0.h[1];
        float xw2 = (float)x0.h[2];
        float xw3 = (float)x0.h[3];
        float sd0 = ra0.x * xw0 + ra0.y * xw1 + ra0.z * xw2 + ra0.w * xw3;
        float sd1 = ra1.x * xw0 + ra1.y * xw1 + ra1.z * xw2 + ra1.w * xw3;
        float sd2 = ra2.x * xw0 + ra2.y * xw1 + ra2.z * xw2 + ra2.w * xw3;
        acc[0]  = fmaf(rs0.x, sd0, acc[0]);
        acc[1]  = fmaf(rs0.y, sd0, acc[1]);
        acc[2]  = fmaf(rs0.z, sd0, acc[2]);
        acc[3]  = fmaf(rs0.w, sd1, acc[3]);
        acc[4]  = fmaf(rs1.x, sd1, acc[4]);
        acc[5]  = fmaf(rs1.y, sd1, acc[5]);
        acc[6]  = fmaf(rs1.z, sd1, acc[6]);
        acc[7]  = fmaf(rs1.w, sd1, acc[7]);
        acc[8]  = fmaf(rs2.x, sd2, acc[8]);
        acc[9]  = fmaf(rs2.y, sd2, acc[9]);
        acc[10] = fmaf(rs2.z, sd2, acc[10]);
        acc[11] = fmaf(rs2.w, sd2, acc[11]);
        acc[12] = fmaf(rs3.x, sd2, acc[12]);
        acc[13] = fmaf(rs3.y, sd2, acc[13]);
        acc[14] = fmaf(rs3.z, sd2, acc[14]);
        x0.u = x1.u;
        x1.u = x2.u;
        j2 = j3;
    }
    bool interior = started_inside && (cur != nextA);
    flush_acc(out, cur, acc, bout, t, interior);
}

extern "C" void kernel_launch(void* const* d_in, const int* in_sizes, int n_in,
                              void* d_out, int out_size, void* d_ws, size_t ws_size,
                              hipStream_t stream) {
    const float* x        = (const float*)d_in[0];
    const float* rbf_ij   = (const float*)d_in[1];
    const float* sph_ij   = (const float*)d_in[2];
    const float* phi_r    = (const float*)d_in[3];
    const int*   idx_i    = (const int*)d_in[4];
    const int*   idx_j    = (const int*)d_in[5];
    const float* pmask    = (const float*)d_in[6];
    const float* W_Q      = (const float*)d_in[7];
    const float* W_K      = (const float*)d_in[8];
    const float* W_in     = (const float*)d_in[9];
    const float* b_in     = (const float*)d_in[10];
    const float* W_f1     = (const float*)d_in[11];
    const float* b_f1     = (const float*)d_in[12];
    const float* W_f2     = (const float*)d_in[13];
    const float* b_f2     = (const float*)d_in[14];
    const float* W_out    = (const float*)d_in[15];
    const float* b_out    = (const float*)d_in[16];
    float* out = (float*)d_out;

    float* ws    = (float*)d_ws;
    float* xh    = ws;                                   // 10000*128
    float* Qbuf  = xh + N_ATOMS * F_DIM;                 // 10000*384
    float* Kbuf  = Qbuf + N_ATOMS * 384;                 // 10000*384
    float* rec   = Kbuf + N_ATOMS * 384;                 // 100000*32 (12.8 MB)
    unsigned short* W2h = (unsigned short*)(rec + (long)N_PAIR * 32); // 12288 bf16
    unsigned short* W2l = W2h + 12288;                    // 12288 bf16
    unsigned short* xwh = (unsigned short*)Qbuf; // reuse Q/K space after k_pair
                                                 // 10000*512 fp16 = 10.24 MB

    k_binit<<<2048, 256, 0, stream>>>(b_out, (float4*)d_out, R_OUT * 128 / 4);
    k_cvt_w2<<<48, 256, 0, stream>>>(W_f2, W2h, W2l);
    k_pack<<<(N_PAIR * 16 + 255) / 256, 256, 0, stream>>>(sph_ij, pmask, rec);
    k_gemm128<<<(N_ATOMS + 127) / 128, 256, 0, stream>>>(x, W_in, b_in, xh, N_ATOMS);
    k_qk<<<(N_ATOMS + 31) / 32, 384, 0, stream>>>(xh, W_Q, W_K, Qbuf, Kbuf);
    k_pair<<<N_PAIR / 16, 256, 0, stream>>>(rbf_ij, phi_r, pmask, idx_i, idx_j,
                                            W_f1, b_f1, W2h, W2l, b_f2,
                                            Qbuf, Kbuf, rec);
    k_xw<<<(N_ATOMS + 31) / 32, 512, 0, stream>>>(xh, W_out, xwh);
    k_aggc<<<N_PAIR / (4 * PPB), 512, 0, stream>>>(xwh, rec, idx_i, idx_j,
                                                   b_out, out);
}